// Round 3
// baseline (474.942 us; speedup 1.0000x reference)
//
#include <hip/hip_runtime.h>

#define N_BATCH 256
#define SEQ     2048
#define L       50
#define CORE    58                  // output rows per block
#define HALO    3                   // iteration dependency radius
#define WROWS   64                  // working rows = 4 tiles x 16
#define SP      72                  // p_s row stride in bf16 (144 B, 16B-aligned)
#define SB      72                  // B row stride in bf16
#define ITER    3

typedef __attribute__((ext_vector_type(8))) short bf16x8;
typedef __attribute__((ext_vector_type(4))) float f32x4;
typedef __attribute__((ext_vector_type(2))) float f32x2;

__device__ __forceinline__ unsigned short f2b(float f) {
    unsigned int u = __builtin_bit_cast(unsigned int, f);
    u += 0x7FFFu + ((u >> 16) & 1u);            // RTNE
    return (unsigned short)(u >> 16);
}

__global__ __launch_bounds__(256, 4) void mfvi_kernel(
    const float* __restrict__ unary,
    const float* __restrict__ mask,
    const float* __restrict__ trans,   // [L][L]
    const float* __restrict__ tstart,  // [L]
    const float* __restrict__ tend,    // [L]
    float* __restrict__ out)
{
    // Bbuf (B staging) is dead after fragment extraction -> reused as fp32 stage
    // buffer for coalesced global<->LDS copies. 18432 B >= 3200*4 B needed.
    __shared__ __attribute__((aligned(16))) unsigned short Bbuf[2 * 64 * SB]; // 18.4 KB
    __shared__ __attribute__((aligned(16))) unsigned short p_s[WROWS * SP];   // 9.2 KB
    __shared__ float ts_s[64], te_s[64];

    unsigned short* BLs = Bbuf;             // BL[n][k] = T[k][n]
    unsigned short* BRs = Bbuf + 64 * SB;   // BR[n][k] = T[n][k]
    float* stage = (float*)Bbuf;

    const int tid   = threadIdx.x;
    const int lane  = tid & 63;
    const int wave  = tid >> 6;
    const int nloc  = lane & 15;
    const int quad  = lane >> 4;
    const int nb    = blockIdx.y;
    const int s0    = blockIdx.x * CORE;
    const int tile0 = s0 - HALO + wave * 16;   // global seq row of this wave's tile row 0

    // ---------- phase A: stage transitions (coalesced read, LDS scatter) ----------
    for (int i = tid; i < L * L; i += 256) {
        int r = i / L, c = i - r * L;
        unsigned short v = f2b(trans[i]);
        BLs[c * SB + r] = v;
        BRs[r * SB + c] = v;
    }
    // zero K-padding k in [L,64): A cols there are nonzero probs only for k<L,
    // but p[k>=L]=0 exactly, so B garbage would still make 0*NaN -> zero it.
    if (tid < 128) {
        unsigned short* p = (tid < 64 ? BLs : BRs) + (tid & 63) * SB;
        for (int k = L; k < 64; ++k) p[k] = 0;
    }
    if (tid < 64) {
        ts_s[tid] = (tid < L) ? tstart[tid] : 0.f;
        te_s[tid] = (tid < L) ? tend[tid]   : 0.f;
    }
    __syncthreads();

    // ---------- phase B: persistent register fragments ----------
    bf16x8 bL[2][4], bR[2][4];
#pragma unroll
    for (int kk = 0; kk < 2; ++kk)
#pragma unroll
        for (int nt = 0; nt < 4; ++nt) {
            int off = (nt * 16 + nloc) * SB + kk * 32 + quad * 8;
            bL[kk][nt] = *(const bf16x8*)&BLs[off];
            bR[kk][nt] = *(const bf16x8*)&BRs[off];
        }
    float ts_r[4], te_r[4];
#pragma unroll
    for (int nt = 0; nt < 4; ++nt) {
        ts_r[nt] = ts_s[nt * 16 + nloc];
        te_r[nt] = te_s[nt * 16 + nloc];
    }
    __syncthreads();   // Bbuf reads done; safe to overwrite as stage

    // ---------- phase C: coalesced unary load -> stage (packed [row][50]) ----------
    const int lo  = (s0 - HALO < 0) ? 0 : s0 - HALO;
    const int hi  = (s0 + CORE + HALO > SEQ) ? SEQ : s0 + CORE + HALO;
    const int cnt = (hi - lo) * L;                         // even
    {
        const f32x2* src = (const f32x2*)(unary + ((size_t)nb * SEQ + lo) * L);
        f32x2* dst = (f32x2*)stage;
        for (int i = tid; i < (cnt >> 1); i += 256) dst[i] = src[i];
    }
    __syncthreads();

    // ---------- scatter stage -> registers (MFMA C-layout) ----------
    float q[4][4], um[4][4], mk[4];
#pragma unroll
    for (int reg = 0; reg < 4; ++reg) {
        int g = tile0 + quad * 4 + reg;
        bool in = (g >= lo) && (g < hi);
        mk[reg] = in ? mask[nb * SEQ + g] : 0.f;
#pragma unroll
        for (int nt = 0; nt < 4; ++nt) {
            int c = nt * 16 + nloc;
            float u = (in && c < L) ? stage[(g - lo) * L + c] : 0.f;
            um[nt][reg] = u * mk[reg];
            q[nt][reg]  = um[nt][reg];
        }
    }

    const int myrow = wave * 16 + quad * 4;
    int slL = wave * 16 + nloc - 1; if (slL < 0)  slL = 0;   // clamped -> don't-care rows
    int slR = wave * 16 + nloc + 1; if (slR > 63) slR = 63;

    // ---------- iterations: global-free ----------
    for (int it = 0; it < ITER; ++it) {
        const bool v3 = (nloc < 2);                           // col 48+nloc < 50
#pragma unroll
        for (int reg = 0; reg < 4; ++reg) {
            float x0 = q[0][reg], x1 = q[1][reg], x2 = q[2][reg];
            float x3 = v3 ? q[3][reg] : -1e30f;
            float m = fmaxf(fmaxf(x0, x1), fmaxf(x2, x3));
            m = fmaxf(m, __shfl_xor(m, 1, 64));
            m = fmaxf(m, __shfl_xor(m, 2, 64));
            m = fmaxf(m, __shfl_xor(m, 4, 64));
            m = fmaxf(m, __shfl_xor(m, 8, 64));
            float e0 = __expf(x0 - m), e1 = __expf(x1 - m);
            float e2 = __expf(x2 - m), e3 = __expf(x3 - m);
            float s = e0 + e1 + e2 + e3;
            s += __shfl_xor(s, 1, 64);
            s += __shfl_xor(s, 2, 64);
            s += __shfl_xor(s, 4, 64);
            s += __shfl_xor(s, 8, 64);
            int g = tile0 + quad * 4 + reg;
            float inv = ((g >= 0) && (g < SEQ)) ? __builtin_amdgcn_rcpf(s) : 0.f;
            unsigned short* row = &p_s[(myrow + reg) * SP];
            row[nloc]      = f2b(e0 * inv);
            row[16 + nloc] = f2b(e1 * inv);
            row[32 + nloc] = f2b(e2 * inv);
            row[48 + nloc] = f2b(e3 * inv);                   // exact 0 for cols >= 50
        }
        __syncthreads();   // p ready

        f32x4 acc[4];
#pragma unroll
        for (int nt = 0; nt < 4; ++nt) {
            acc[nt][0] = 0.f; acc[nt][1] = 0.f; acc[nt][2] = 0.f; acc[nt][3] = 0.f;
        }
#pragma unroll
        for (int kk = 0; kk < 2; ++kk) {
            bf16x8 aL = *(const bf16x8*)&p_s[slL * SP + kk * 32 + quad * 8];
            bf16x8 aR = *(const bf16x8*)&p_s[slR * SP + kk * 32 + quad * 8];
#pragma unroll
            for (int nt = 0; nt < 4; ++nt) {
                acc[nt] = __builtin_amdgcn_mfma_f32_16x16x32_bf16(aL, bL[kk][nt], acc[nt], 0, 0, 0);
                acc[nt] = __builtin_amdgcn_mfma_f32_16x16x32_bf16(aR, bR[kk][nt], acc[nt], 0, 0, 0);
            }
        }
        __syncthreads();   // p_s reads done before next iteration's writes

#pragma unroll
        for (int reg = 0; reg < 4; ++reg) {
            int g = tile0 + quad * 4 + reg;
#pragma unroll
            for (int nt = 0; nt < 4; ++nt) {
                float v = um[nt][reg] + acc[nt][reg];
                if (g == 0) v += ts_r[nt];
                if (g >= 1) v += te_r[nt];
                q[nt][reg] = v * mk[reg];
            }
        }
    }

    // ---------- gather core rows -> stage (packed), then coalesced store ----------
    const int gcnt = (SEQ - s0 < CORE) ? (SEQ - s0) : CORE;
#pragma unroll
    for (int reg = 0; reg < 4; ++reg) {
        int g = tile0 + quad * 4 + reg;
        if (g >= s0 && g < s0 + gcnt) {
#pragma unroll
            for (int nt = 0; nt < 4; ++nt) {
                int c = nt * 16 + nloc;
                if (c < L) stage[(g - s0) * L + c] = q[nt][reg];
            }
        }
    }
    __syncthreads();
    {
        const int ocnt = gcnt * L;                       // multiple of 4
        f32x4* dst = (f32x4*)(out + ((size_t)nb * SEQ + s0) * L);  // 16B-aligned
        const f32x4* src = (const f32x4*)stage;
        for (int i = tid; i < (ocnt >> 2); i += 256) dst[i] = src[i];
    }
}

extern "C" void kernel_launch(void* const* d_in, const int* in_sizes, int n_in,
                              void* d_out, int out_size, void* d_ws, size_t ws_size,
                              hipStream_t stream) {
    const float* unary  = (const float*)d_in[0];
    const float* mask   = (const float*)d_in[1];
    const float* trans  = (const float*)d_in[2];
    const float* tstart = (const float*)d_in[3];
    const float* tend   = (const float*)d_in[4];
    float* out = (float*)d_out;

    dim3 grid((SEQ + CORE - 1) / CORE, N_BATCH);   // 36 x 256
    mfvi_kernel<<<grid, dim3(256), 0, stream>>>(unary, mask, trans, tstart, tend, out);
}

// Round 4
// 292.965 us; speedup vs baseline: 1.6212x; 1.6212x over previous
//
#include <hip/hip_runtime.h>

#define N_BATCH 256
#define SEQ     2048
#define L       50
#define CORE    58                  // output rows per block
#define HALO    3                   // iteration dependency radius
#define SP      72                  // p_s row stride in bf16 (144 B, 16B-aligned)
#define SB      72                  // B row stride in bf16
#define ITER    3

typedef __attribute__((ext_vector_type(8))) short bf16x8;
typedef __attribute__((ext_vector_type(4))) float f32x4;
typedef __attribute__((ext_vector_type(2))) float f32x2;

__device__ __forceinline__ unsigned short f2b(float f) {
    unsigned int u = __builtin_bit_cast(unsigned int, f);
    u += 0x7FFFu + ((u >> 16) & 1u);            // RTNE
    return (unsigned short)(u >> 16);
}

// waves_per_eu pinned to (3,3): allocator budgets ~170 VGPRs and will NOT
// gamble on 8 waves/EU (64 regs) and spill ~70 regs to scratch — that spill
// traffic was rounds 2/3's 500+ MB of HBM writes.
__global__ __attribute__((amdgpu_waves_per_eu(3, 3))) __launch_bounds__(256)
void mfvi_kernel(
    const float* __restrict__ unary,
    const float* __restrict__ mask,
    const float* __restrict__ trans,   // [L][L]
    const float* __restrict__ tstart,  // [L]
    const float* __restrict__ tend,    // [L]
    float* __restrict__ out)
{
    // Bbuf: B staging -> (after frag extraction) fp32 stage for coalesced IO
    __shared__ __attribute__((aligned(16))) unsigned short Bbuf[2 * 64 * SB]; // 18432 B
    __shared__ __attribute__((aligned(16))) unsigned short p_s[64 * SP];      // 9216 B

    unsigned short* BLs = Bbuf;             // BL[n][k] = T[k][n]
    unsigned short* BRs = Bbuf + 64 * SB;   // BR[n][k] = T[n][k]
    float* stage = (float*)Bbuf;

    const int tid   = threadIdx.x;
    const int lane  = tid & 63;
    const int wave  = tid >> 6;
    const int nloc  = lane & 15;
    const int quad  = lane >> 4;
    const int nb    = blockIdx.y;
    const int s0    = blockIdx.x * CORE;
    const int tile0 = s0 - HALO + wave * 16;   // global seq row of this wave's tile row 0

    // ---------- phase A: stage transitions (coalesced read, LDS scatter) ----------
    for (int i = tid; i < L * L; i += 256) {
        int r = i / L, c = i - r * L;
        unsigned short v = f2b(trans[i]);
        BLs[c * SB + r] = v;
        BRs[r * SB + c] = v;
    }
    // zero K-padding k in [L,64) for all n-rows (p cols there are exact 0 anyway,
    // but avoid NaN*0 pattern risk)
    if (tid < 128) {
        unsigned short* p = (tid < 64 ? BLs : BRs) + (tid & 63) * SB;
        for (int k = L; k < 64; ++k) p[k] = 0;
    }
    __syncthreads();

    // ---------- phase B: B fragments -> registers (64 VGPRs, persistent) ----------
    bf16x8 bL[2][4], bR[2][4];
#pragma unroll
    for (int kk = 0; kk < 2; ++kk)
#pragma unroll
        for (int nt = 0; nt < 4; ++nt) {
            int off = (nt * 16 + nloc) * SB + kk * 32 + quad * 8;
            bL[kk][nt] = *(const bf16x8*)&BLs[off];
            bR[kk][nt] = *(const bf16x8*)&BRs[off];
        }
    __syncthreads();   // Bbuf reads done; safe to overwrite as stage

    // ---------- phase C: coalesced unary load -> stage (packed [row][50]) ----------
    const int lo  = (s0 - HALO < 0) ? 0 : s0 - HALO;
    const int hi  = (s0 + CORE + HALO > SEQ) ? SEQ : s0 + CORE + HALO;
    {
        const int cnt = (hi - lo) * L;                     // even
        const f32x2* src = (const f32x2*)(unary + ((size_t)nb * SEQ + lo) * L);
        f32x2* dst = (f32x2*)stage;
        for (int i = tid; i < (cnt >> 1); i += 256) dst[i] = src[i];
    }
    __syncthreads();

    // ---------- phase D: q / umm / mk registers (MFMA C-layout) ----------
    // umm = (unary*mask + bnd)*mask, bnd = ts at g==0, te at g>=1.
    // epilogue then is just q = umm + mk*acc.
    float q[4][4], umm[4][4], mk[4];
#pragma unroll
    for (int reg = 0; reg < 4; ++reg) {
        int g = tile0 + quad * 4 + reg;
        bool in = (g >= lo) && (g < hi);
        mk[reg] = in ? mask[nb * SEQ + g] : 0.f;
#pragma unroll
        for (int nt = 0; nt < 4; ++nt) {
            int c = nt * 16 + nloc;
            bool cv = in && (c < L);
            float u   = cv ? stage[(g - lo) * L + c] : 0.f;
            float bnd = cv ? ((g == 0) ? tstart[c] : tend[c]) : 0.f;
            float qv  = u * mk[reg];
            q[nt][reg]   = qv;
            umm[nt][reg] = (qv + bnd) * mk[reg];
        }
    }

    const int myrow = wave * 16 + quad * 4;
    int slL = wave * 16 + nloc - 1; if (slL < 0)  slL = 0;   // clamped -> don't-care rows
    int slR = wave * 16 + nloc + 1; if (slR > 63) slR = 63;

    // ---------- iterations: global-free, spill-free ----------
    for (int it = 0; it < ITER; ++it) {
        // softmax without max-subtraction (|q| <= ~20 mathematically; exp safe in fp32)
        const bool v3 = (nloc < 2);                           // col 48+nloc < 50
#pragma unroll
        for (int reg = 0; reg < 4; ++reg) {
            float e0 = __expf(q[0][reg]);
            float e1 = __expf(q[1][reg]);
            float e2 = __expf(q[2][reg]);
            float e3 = v3 ? __expf(q[3][reg]) : 0.f;
            float s = e0 + e1 + e2 + e3;
            s += __shfl_xor(s, 1, 64);
            s += __shfl_xor(s, 2, 64);
            s += __shfl_xor(s, 4, 64);
            s += __shfl_xor(s, 8, 64);
            int g = tile0 + quad * 4 + reg;
            float inv = ((g >= 0) && (g < SEQ)) ? __builtin_amdgcn_rcpf(s) : 0.f;
            unsigned short* row = &p_s[(myrow + reg) * SP];
            row[nloc]      = f2b(e0 * inv);
            row[16 + nloc] = f2b(e1 * inv);
            row[32 + nloc] = f2b(e2 * inv);
            row[48 + nloc] = f2b(e3 * inv);                   // exact 0 for cols >= 50
        }
        __syncthreads();   // p ready

        f32x4 acc[4];
#pragma unroll
        for (int nt = 0; nt < 4; ++nt) {
            acc[nt][0] = 0.f; acc[nt][1] = 0.f; acc[nt][2] = 0.f; acc[nt][3] = 0.f;
        }
#pragma unroll
        for (int kk = 0; kk < 2; ++kk) {
            bf16x8 aL = *(const bf16x8*)&p_s[slL * SP + kk * 32 + quad * 8];
            bf16x8 aR = *(const bf16x8*)&p_s[slR * SP + kk * 32 + quad * 8];
#pragma unroll
            for (int nt = 0; nt < 4; ++nt) {
                acc[nt] = __builtin_amdgcn_mfma_f32_16x16x32_bf16(aL, bL[kk][nt], acc[nt], 0, 0, 0);
                acc[nt] = __builtin_amdgcn_mfma_f32_16x16x32_bf16(aR, bR[kk][nt], acc[nt], 0, 0, 0);
            }
        }
        __syncthreads();   // p_s reads done before next iteration's writes

        // epilogue: one FMA per element
#pragma unroll
        for (int reg = 0; reg < 4; ++reg)
#pragma unroll
            for (int nt = 0; nt < 4; ++nt)
                q[nt][reg] = umm[nt][reg] + mk[reg] * acc[nt][reg];
    }

    // ---------- gather core rows -> stage (packed), coalesced store ----------
    const int gcnt = (SEQ - s0 < CORE) ? (SEQ - s0) : CORE;
#pragma unroll
    for (int reg = 0; reg < 4; ++reg) {
        int g = tile0 + quad * 4 + reg;
        if (g >= s0 && g < s0 + gcnt) {
#pragma unroll
            for (int nt = 0; nt < 4; ++nt) {
                int c = nt * 16 + nloc;
                if (c < L) stage[(g - s0) * L + c] = q[nt][reg];
            }
        }
    }
    __syncthreads();
    {
        const int ocnt = gcnt * L;                                 // multiple of 4
        f32x4* dst = (f32x4*)(out + ((size_t)nb * SEQ + s0) * L);  // 16B-aligned
        const f32x4* src = (const f32x4*)stage;
        for (int i = tid; i < (ocnt >> 2); i += 256) dst[i] = src[i];
    }
}

extern "C" void kernel_launch(void* const* d_in, const int* in_sizes, int n_in,
                              void* d_out, int out_size, void* d_ws, size_t ws_size,
                              hipStream_t stream) {
    const float* unary  = (const float*)d_in[0];
    const float* mask   = (const float*)d_in[1];
    const float* trans  = (const float*)d_in[2];
    const float* tstart = (const float*)d_in[3];
    const float* tend   = (const float*)d_in[4];
    float* out = (float*)d_out;

    dim3 grid((SEQ + CORE - 1) / CORE, N_BATCH);   // 36 x 256
    mfvi_kernel<<<grid, dim3(256), 0, stream>>>(unary, mask, trans, tstart, tend, out);
}